// Round 3
// baseline (273.737 us; speedup 1.0000x reference)
//
#include <hip/hip_runtime.h>

#define DD 128
#define KK 384
#define NG 512

typedef __attribute__((ext_vector_type(8))) short bf16x8;
typedef __attribute__((ext_vector_type(4))) float f32x4;

__device__ __forceinline__ float bf2f(unsigned short u) {
  return __uint_as_float(((unsigned int)u) << 16);
}
__device__ __forceinline__ unsigned short f2bf(float f) {
  unsigned int x = __float_as_uint(f);
  x += 0x7fffu + ((x >> 16) & 1u);
  return (unsigned short)(x >> 16);
}

__global__ void k_zero2(int* __restrict__ a, int* __restrict__ b,
                        int* __restrict__ gcur, int n) {
  int i = blockIdx.x * blockDim.x + threadIdx.x;
  if (i < n) { a[i] = 0; b[i] = 0; }
  if (i == 0) *gcur = 0;
}

__global__ void k_count(const int* __restrict__ dst, int* __restrict__ counts, int E) {
  int e = blockIdx.x * blockDim.x + threadIdx.x;
  if (e < E) atomicAdd(counts + dst[e], 1);
}

__global__ void k_partition(const int* __restrict__ counts, int* __restrict__ row_start,
                            int* __restrict__ gcur, int n) {
  int i = blockIdx.x * blockDim.x + threadIdx.x;
  int lane = threadIdx.x & 63;
  int v = (i < n) ? counts[i] : 0;
  int s = v;
#pragma unroll
  for (int off = 1; off < 64; off <<= 1) {
    int t = __shfl_up(s, off);
    if (lane >= off) s += t;
  }
  int total = __shfl(s, 63);
  int base = 0;
  if (lane == 63) base = atomicAdd(gcur, total);
  base = __shfl(base, 63);
  if (i < n) row_start[i] = base + s - v;
}

__global__ void k_scatter(const int* __restrict__ srcv, const int* __restrict__ dstv,
                          const int* __restrict__ row_start, int* __restrict__ cursor,
                          int* __restrict__ csr, int E) {
  int e = blockIdx.x * blockDim.x + threadIdx.x;
  if (e < E) {
    int d = dstv[e];
    int pos = row_start[d] + atomicAdd(cursor + d, 1);
    csr[pos] = srcv[e];
  }
}

__global__ void k_convert(const float* __restrict__ h, const float* __restrict__ x,
                          unsigned short* __restrict__ hbf, unsigned short* __restrict__ xbf,
                          int n128, int mpad128) {
  int i = (blockIdx.x * blockDim.x + threadIdx.x) * 4;
  if (i >= mpad128) return;
  ushort4 ho, xo;
  if (i < n128) {
    float4 hv = *(const float4*)(h + i);
    float4 xv = *(const float4*)(x + i);
    ho = make_ushort4(f2bf(hv.x), f2bf(hv.y), f2bf(hv.z), f2bf(hv.w));
    xo = make_ushort4(f2bf(xv.x), f2bf(xv.y), f2bf(xv.z), f2bf(xv.w));
  } else {
    ho = make_ushort4(0, 0, 0, 0);
    xo = make_ushort4(0, 0, 0, 0);
  }
  *(ushort4*)(hbf + i) = ho;
  *(ushort4*)(xbf + i) = xo;
}

// One wave per node. 4 neighbor-groups x 16 lanes x bf16x8(16B) per row.
__global__ void k_agg(const unsigned short* __restrict__ hbf, const int* __restrict__ row_start,
                      const int* __restrict__ counts, const int* __restrict__ csr,
                      unsigned short* __restrict__ aggbf, int n, int mpad) {
  int wave = (blockIdx.x * blockDim.x + threadIdx.x) >> 6;
  int lane = threadIdx.x & 63;
  if (wave >= mpad) return;
  int g = lane >> 4;
  int t = lane & 15;
  float acc[8] = {0.f, 0.f, 0.f, 0.f, 0.f, 0.f, 0.f, 0.f};
  if (wave < n) {
    int s = row_start[wave], deg = counts[wave];
    int e = s + deg;
    for (int j = s; j < e; j += 4) {
      int jj = j + g;
      if (jj < e) {
        int src = csr[jj];
        bf16x8 v = *(const bf16x8*)(hbf + (size_t)src * DD + t * 8);
#pragma unroll
        for (int q = 0; q < 8; ++q) acc[q] += bf2f((unsigned short)v[q]);
      }
    }
#pragma unroll
    for (int q = 0; q < 8; ++q) {
      acc[q] += __shfl_xor(acc[q], 16);
      acc[q] += __shfl_xor(acc[q], 32);
    }
    float inv = 1.f / fmaxf((float)deg, 1.f);
#pragma unroll
    for (int q = 0; q < 8; ++q) acc[q] *= inv;
  }
  if (g == 0) {
    bf16x8 o;
#pragma unroll
    for (int q = 0; q < 8; ++q) o[q] = (short)f2bf(acc[q]);
    *(bf16x8*)(aggbf + (size_t)wave * DD + t * 8) = o;
  }
}

__global__ void k_fusew(const float* __restrict__ Wg0, const float* __restrict__ Wg1,
                        const float* __restrict__ Wg2, const float* __restrict__ Wg3,
                        const float* __restrict__ Wl0, const float* __restrict__ Wl1,
                        const float* __restrict__ Wl2, const float* __restrict__ Wl3,
                        const float* __restrict__ Wr0, const float* __restrict__ Wr1,
                        const float* __restrict__ Wr2, const float* __restrict__ Wr3,
                        const float* __restrict__ bg0, const float* __restrict__ bg1,
                        const float* __restrict__ bg2, const float* __restrict__ bg3,
                        const float* __restrict__ bl0, const float* __restrict__ bl1,
                        const float* __restrict__ bl2, const float* __restrict__ bl3,
                        unsigned short* __restrict__ Ut, float* __restrict__ bias) {
  int id = blockIdx.x * blockDim.x + threadIdx.x;
  if (id >= NG * KK) return;
  int nn = id / KK, k = id % KK;
  int g = nn >> 7, c = nn & 127;
  const float* Wg = g == 0 ? Wg0 : g == 1 ? Wg1 : g == 2 ? Wg2 : Wg3;
  const float* Wl = g == 0 ? Wl0 : g == 1 ? Wl1 : g == 2 ? Wl2 : Wl3;
  const float* Wr = g == 0 ? Wr0 : g == 1 ? Wr1 : g == 2 ? Wr2 : Wr3;
  float v;
  if (k < 128)      v = Wg[k * DD + c] + Wr[k * DD + c];
  else if (k < 256) v = Wg[k * DD + c];
  else              v = Wl[(k - 256) * DD + c];
  Ut[(size_t)nn * KK + k] = f2bf(v);
  if (k == 0) {
    const float* bgp = g == 0 ? bg0 : g == 1 ? bg1 : g == 2 ? bg2 : bg3;
    const float* blp = g == 0 ? bl0 : g == 1 ? bl1 : g == 2 ? bl2 : bl3;
    bias[nn] = bgp[c] + blp[c];
  }
}

__device__ __forceinline__ void gload16(const void* g, void* l) {
  __builtin_amdgcn_global_load_lds((__attribute__((address_space(1))) void*)(void*)g,
                                   (__attribute__((address_space(3))) void*)l, 16, 0, 0);
}

// Fused GEMM + LSTM-gate + LayerNorm epilogue.
// BM=128, BN=512(all gates), BK=64, 512 threads = 8 waves (2M x 4N, wave tile 64x128).
__global__ __launch_bounds__(512) void k_gemm_fused(
    const unsigned short* __restrict__ hbf, const unsigned short* __restrict__ xbf,
    const unsigned short* __restrict__ aggbf, const unsigned short* __restrict__ Ut,
    const float* __restrict__ bias, const float* __restrict__ cell,
    const float* __restrict__ gamma, const float* __restrict__ beta,
    float* __restrict__ out, int nrows) {
  __shared__ unsigned short As[128 * 64];  // 16 KB
  __shared__ unsigned short Bs[512 * 64];  // 64 KB (reused as 64x512 gate tile)
  int m0 = blockIdx.x * 128;
  int tid = threadIdx.x;
  int w = tid >> 6, lane = tid & 63;
  int wr = w >> 2, wc = w & 3;  // 2M x 4N wave grid
  int rg = lane >> 4;
  f32x4 acc[4][8] = {};

  int srow = tid >> 3;      // staging row within 64-row round
  int sslot = tid & 7;      // 16B slot within 128B row

  for (int ks = 0; ks < 6; ++ks) {
    const unsigned short* Ab = ks < 2 ? hbf : (ks < 4 ? xbf : aggbf);
    int akoff = (ks & 1) * 128;
    int bkoff = ks * 128;
#pragma unroll
    for (int p = 0; p < 2; ++p) {
      int r = p * 64 + srow;
      const char* ga = (const char*)Ab + (size_t)(m0 + r) * 256 + akoff + ((sslot ^ (r & 7)) * 16);
      gload16(ga, (char*)As + p * 8192 + tid * 16);
    }
#pragma unroll
    for (int p = 0; p < 8; ++p) {
      int r = p * 64 + srow;
      const char* gb = (const char*)Ut + (size_t)r * 768 + bkoff + ((sslot ^ (r & 7)) * 16);
      gload16(gb, (char*)Bs + p * 8192 + tid * 16);
    }
    asm volatile("s_waitcnt vmcnt(0)" ::: "memory");
    __syncthreads();

    bf16x8 af[4][2];
#pragma unroll
    for (int mi = 0; mi < 4; ++mi) {
      int r = wr * 64 + mi * 16 + (lane & 15);
#pragma unroll
      for (int k2 = 0; k2 < 2; ++k2) {
        int s = (k2 * 4 + rg) ^ (r & 7);
        af[mi][k2] = *(const bf16x8*)((const char*)As + r * 128 + s * 16);
      }
    }
#pragma unroll
    for (int ni = 0; ni < 8; ++ni) {
      int rb = wc * 128 + ni * 16 + (lane & 15);
      int s0 = (0 * 4 + rg) ^ (rb & 7);
      int s1 = (1 * 4 + rg) ^ (rb & 7);
      bf16x8 bq0 = *(const bf16x8*)((const char*)Bs + rb * 128 + s0 * 16);
      bf16x8 bq1 = *(const bf16x8*)((const char*)Bs + rb * 128 + s1 * 16);
#pragma unroll
      for (int mi = 0; mi < 4; ++mi) {
        acc[mi][ni] = __builtin_amdgcn_mfma_f32_16x16x32_bf16(af[mi][0], bq0, acc[mi][ni], 0, 0, 0);
        acc[mi][ni] = __builtin_amdgcn_mfma_f32_16x16x32_bf16(af[mi][1], bq1, acc[mi][ni], 0, 0, 0);
      }
    }
    __syncthreads();
  }

  // bias into acc
  float bias_v[8];
#pragma unroll
  for (int ni = 0; ni < 8; ++ni) bias_v[ni] = bias[wc * 128 + ni * 16 + (lane & 15)];
#pragma unroll
  for (int mi = 0; mi < 4; ++mi)
#pragma unroll
    for (int ni = 0; ni < 8; ++ni)
#pragma unroll
      for (int j = 0; j < 4; ++j) acc[mi][ni][j] += bias_v[ni];

  unsigned short* Gs = Bs;  // 64 rows x 512 cols bf16, XOR-swizzled
  const float eps = 1e-5f;

  for (int pass = 0; pass < 2; ++pass) {
    __syncthreads();
    if (wr == pass) {
#pragma unroll
      for (int mi = 0; mi < 4; ++mi)
#pragma unroll
        for (int ni = 0; ni < 8; ++ni)
#pragma unroll
          for (int j = 0; j < 4; ++j) {
            int rowp = mi * 16 + rg * 4 + j;
            int col = wc * 128 + ni * 16 + (lane & 15);
            int byte = (rowp * 1024 + col * 2) ^ ((rowp & 7) << 4);
            *(unsigned short*)((char*)Gs + byte) = f2bf(acc[mi][ni][j]);
          }
    }
    __syncthreads();
#pragma unroll
    for (int t = 0; t < 8; ++t) {
      int rr = w * 8 + t;
      int rowg = m0 + pass * 64 + rr;
      if (rowg >= nrows) continue;  // wave-uniform
      int c = lane * 2;
      int sw = (rr & 7) << 4;
      ushort2 fu = *(const ushort2*)((char*)Gs + ((rr * 1024 + 0 + lane * 4) ^ sw));
      ushort2 iu = *(const ushort2*)((char*)Gs + ((rr * 1024 + 256 + lane * 4) ^ sw));
      ushort2 cu = *(const ushort2*)((char*)Gs + ((rr * 1024 + 512 + lane * 4) ^ sw));
      ushort2 ou = *(const ushort2*)((char*)Gs + ((rr * 1024 + 768 + lane * 4) ^ sw));
      float2 cv = *(const float2*)(cell + (size_t)rowg * DD + c);
      float f0 = 1.f / (1.f + expf(-bf2f(fu.x)));
      float f1 = 1.f / (1.f + expf(-bf2f(fu.y)));
      float i0 = 1.f / (1.f + expf(-bf2f(iu.x)));
      float i1 = 1.f / (1.f + expf(-bf2f(iu.y)));
      float t0 = tanhf(bf2f(cu.x));
      float t1 = tanhf(bf2f(cu.y));
      float o0 = 1.f / (1.f + expf(-bf2f(ou.x)));
      float o1 = 1.f / (1.f + expf(-bf2f(ou.y)));
      float cn0 = f0 * cv.x + i0 * t0;
      float cn1 = f1 * cv.y + i1 * t1;
      float y0 = o0 * tanhf(cn0);
      float y1 = o1 * tanhf(cn1);
      float s = y0 + y1, s2 = y0 * y0 + y1 * y1;
#pragma unroll
      for (int off = 1; off < 64; off <<= 1) {
        s += __shfl_xor(s, off);
        s2 += __shfl_xor(s2, off);
      }
      float mean = s * (1.f / 128.f);
      float var = s2 * (1.f / 128.f) - mean * mean;
      float rstd = rsqrtf(var + eps);
      float2 gm = *(const float2*)(gamma + c);
      float2 bt = *(const float2*)(beta + c);
      float h0 = (y0 - mean) * rstd * gm.x + bt.x;
      float h1 = (y1 - mean) * rstd * gm.y + bt.y;
      *(float2*)(out + (size_t)rowg * DD + c) = make_float2(h0, h1);
      *(float2*)(out + (size_t)nrows * DD + (size_t)rowg * DD + c) = make_float2(cn0, cn1);
    }
  }
}

extern "C" void kernel_launch(void* const* d_in, const int* in_sizes, int n_in,
                              void* d_out, int out_size, void* d_ws, size_t ws_size,
                              hipStream_t stream) {
  const float* h = (const float*)d_in[0];
  const float* cellp = (const float*)d_in[1];
  const float* x = (const float*)d_in[2];
  const int* edge = (const int*)d_in[3];
  const float* Wg0 = (const float*)d_in[4];
  const float* bg0 = (const float*)d_in[5];
  const float* Wg1 = (const float*)d_in[6];
  const float* bg1 = (const float*)d_in[7];
  const float* Wg2 = (const float*)d_in[8];
  const float* bg2 = (const float*)d_in[9];
  const float* Wg3 = (const float*)d_in[10];
  const float* bg3 = (const float*)d_in[11];
  const float* Wl0 = (const float*)d_in[12];
  const float* bl0 = (const float*)d_in[13];
  const float* Wr0 = (const float*)d_in[14];
  const float* Wl1 = (const float*)d_in[15];
  const float* bl1 = (const float*)d_in[16];
  const float* Wr1 = (const float*)d_in[17];
  const float* Wl2 = (const float*)d_in[18];
  const float* bl2 = (const float*)d_in[19];
  const float* Wr2 = (const float*)d_in[20];
  const float* Wl3 = (const float*)d_in[21];
  const float* bl3 = (const float*)d_in[22];
  const float* Wr3 = (const float*)d_in[23];
  const float* gamma = (const float*)d_in[24];
  const float* beta = (const float*)d_in[25];

  int N = in_sizes[0] / DD;
  int E = in_sizes[3] / 2;
  int Mpad = ((N + 127) / 128) * 128;

  char* ws = (char*)d_ws;
  size_t off = 0;
  auto alloc = [&](size_t b) {
    char* p = ws + off;
    off += (b + 255) & ~(size_t)255;
    return p;
  };
  int* counts = (int*)alloc((size_t)N * 4);
  int* cursor = (int*)alloc((size_t)N * 4);
  int* row_start = (int*)alloc((size_t)N * 4);
  int* gcur = (int*)alloc(4);
  int* csr = (int*)alloc((size_t)E * 4);
  unsigned short* hbf = (unsigned short*)alloc((size_t)Mpad * DD * 2);
  unsigned short* xbf = (unsigned short*)alloc((size_t)Mpad * DD * 2);
  unsigned short* aggbf = (unsigned short*)alloc((size_t)Mpad * DD * 2);
  unsigned short* Ut = (unsigned short*)alloc((size_t)NG * KK * 2);
  float* bias = (float*)alloc((size_t)NG * 4);
  (void)ws_size;
  (void)n_in;
  (void)out_size;

  const int* esrc = edge;
  const int* edst = edge + E;

  k_zero2<<<(N + 255) / 256, 256, 0, stream>>>(counts, cursor, gcur, N);
  k_count<<<(E + 255) / 256, 256, 0, stream>>>(edst, counts, E);
  k_partition<<<(N + 255) / 256, 256, 0, stream>>>(counts, row_start, gcur, N);
  k_scatter<<<(E + 255) / 256, 256, 0, stream>>>(esrc, edst, row_start, cursor, csr, E);
  k_convert<<<((Mpad * DD / 4) + 255) / 256, 256, 0, stream>>>(h, x, hbf, xbf, N * DD, Mpad * DD);
  k_agg<<<(Mpad + 3) / 4, 256, 0, stream>>>(hbf, row_start, counts, csr, aggbf, N, Mpad);
  k_fusew<<<(NG * KK + 255) / 256, 256, 0, stream>>>(
      Wg0, Wg1, Wg2, Wg3, Wl0, Wl1, Wl2, Wl3, Wr0, Wr1, Wr2, Wr3,
      bg0, bg1, bg2, bg3, bl0, bl1, bl2, bl3, Ut, bias);
  k_gemm_fused<<<Mpad / 128, 512, 0, stream>>>(hbf, xbf, aggbf, Ut, bias, cellp,
                                               gamma, beta, (float*)d_out, N);
}

// Round 4
// 211.890 us; speedup vs baseline: 1.2919x; 1.2919x over previous
//
#include <hip/hip_runtime.h>

#define DD 128
#define KK 384
#define NG 512

typedef __attribute__((ext_vector_type(8))) short bf16x8;
typedef __attribute__((ext_vector_type(4))) float f32x4;

__device__ __forceinline__ float bf2f(unsigned short u) {
  return __uint_as_float(((unsigned int)u) << 16);
}
__device__ __forceinline__ unsigned short f2bf(float f) {
  unsigned int x = __float_as_uint(f);
  x += 0x7fffu + ((x >> 16) & 1u);
  return (unsigned short)(x >> 16);
}
__device__ __forceinline__ float fsigmoid(float v) {
  return 1.f / (1.f + __expf(-v));
}
__device__ __forceinline__ float ftanh(float v) {
  float t = __expf(2.f * v);
  return (t - 1.f) / (t + 1.f);
}

__global__ void k_zero2(int* __restrict__ a, int* __restrict__ b,
                        int* __restrict__ gcur, int n) {
  int i = blockIdx.x * blockDim.x + threadIdx.x;
  if (i < n) { a[i] = 0; b[i] = 0; }
  if (i == 0) *gcur = 0;
}

__global__ void k_count(const int* __restrict__ dst, int* __restrict__ counts, int E) {
  int e = blockIdx.x * blockDim.x + threadIdx.x;
  if (e < E) atomicAdd(counts + dst[e], 1);
}

__global__ void k_partition(const int* __restrict__ counts, int* __restrict__ row_start,
                            int* __restrict__ gcur, int n) {
  int i = blockIdx.x * blockDim.x + threadIdx.x;
  int lane = threadIdx.x & 63;
  int v = (i < n) ? counts[i] : 0;
  int s = v;
#pragma unroll
  for (int off = 1; off < 64; off <<= 1) {
    int t = __shfl_up(s, off);
    if (lane >= off) s += t;
  }
  int total = __shfl(s, 63);
  int base = 0;
  if (lane == 63) base = atomicAdd(gcur, total);
  base = __shfl(base, 63);
  if (i < n) row_start[i] = base + s - v;
}

__global__ void k_scatter(const int* __restrict__ srcv, const int* __restrict__ dstv,
                          const int* __restrict__ row_start, int* __restrict__ cursor,
                          int* __restrict__ csr, int E) {
  int e = blockIdx.x * blockDim.x + threadIdx.x;
  if (e < E) {
    int d = dstv[e];
    int pos = row_start[d] + atomicAdd(cursor + d, 1);
    csr[pos] = srcv[e];
  }
}

__global__ void k_convert(const float* __restrict__ h, const float* __restrict__ x,
                          unsigned short* __restrict__ hbf, unsigned short* __restrict__ xbf,
                          int n128, int mpad128) {
  int i = (blockIdx.x * blockDim.x + threadIdx.x) * 4;
  if (i >= mpad128) return;
  ushort4 ho, xo;
  if (i < n128) {
    float4 hv = *(const float4*)(h + i);
    float4 xv = *(const float4*)(x + i);
    ho = make_ushort4(f2bf(hv.x), f2bf(hv.y), f2bf(hv.z), f2bf(hv.w));
    xo = make_ushort4(f2bf(xv.x), f2bf(xv.y), f2bf(xv.z), f2bf(xv.w));
  } else {
    ho = make_ushort4(0, 0, 0, 0);
    xo = make_ushort4(0, 0, 0, 0);
  }
  *(ushort4*)(hbf + i) = ho;
  *(ushort4*)(xbf + i) = xo;
}

// One wave per node. 4 neighbor-groups x 16 lanes x bf16x8(16B) per row.
__global__ void k_agg(const unsigned short* __restrict__ hbf, const int* __restrict__ row_start,
                      const int* __restrict__ counts, const int* __restrict__ csr,
                      unsigned short* __restrict__ aggbf, int n, int mpad) {
  int wave = (blockIdx.x * blockDim.x + threadIdx.x) >> 6;
  int lane = threadIdx.x & 63;
  if (wave >= mpad) return;
  int g = lane >> 4;
  int t = lane & 15;
  float acc[8] = {0.f, 0.f, 0.f, 0.f, 0.f, 0.f, 0.f, 0.f};
  if (wave < n) {
    int s = row_start[wave], deg = counts[wave];
    int e = s + deg;
    for (int j = s; j < e; j += 4) {
      int jj = j + g;
      if (jj < e) {
        int src = csr[jj];
        bf16x8 v = *(const bf16x8*)(hbf + (size_t)src * DD + t * 8);
#pragma unroll
        for (int q = 0; q < 8; ++q) acc[q] += bf2f((unsigned short)v[q]);
      }
    }
#pragma unroll
    for (int q = 0; q < 8; ++q) {
      acc[q] += __shfl_xor(acc[q], 16);
      acc[q] += __shfl_xor(acc[q], 32);
    }
    float inv = 1.f / fmaxf((float)deg, 1.f);
#pragma unroll
    for (int q = 0; q < 8; ++q) acc[q] *= inv;
  }
  if (g == 0) {
    bf16x8 o;
#pragma unroll
    for (int q = 0; q < 8; ++q) o[q] = (short)f2bf(acc[q]);
    *(bf16x8*)(aggbf + (size_t)wave * DD + t * 8) = o;
  }
}

__global__ void k_fusew(const float* __restrict__ Wg0, const float* __restrict__ Wg1,
                        const float* __restrict__ Wg2, const float* __restrict__ Wg3,
                        const float* __restrict__ Wl0, const float* __restrict__ Wl1,
                        const float* __restrict__ Wl2, const float* __restrict__ Wl3,
                        const float* __restrict__ Wr0, const float* __restrict__ Wr1,
                        const float* __restrict__ Wr2, const float* __restrict__ Wr3,
                        const float* __restrict__ bg0, const float* __restrict__ bg1,
                        const float* __restrict__ bg2, const float* __restrict__ bg3,
                        const float* __restrict__ bl0, const float* __restrict__ bl1,
                        const float* __restrict__ bl2, const float* __restrict__ bl3,
                        unsigned short* __restrict__ Ut, float* __restrict__ bias) {
  int id = blockIdx.x * blockDim.x + threadIdx.x;
  if (id >= NG * KK) return;
  int nn = id / KK, k = id % KK;
  int g = nn >> 7, c = nn & 127;
  const float* Wg = g == 0 ? Wg0 : g == 1 ? Wg1 : g == 2 ? Wg2 : Wg3;
  const float* Wl = g == 0 ? Wl0 : g == 1 ? Wl1 : g == 2 ? Wl2 : Wl3;
  const float* Wr = g == 0 ? Wr0 : g == 1 ? Wr1 : g == 2 ? Wr2 : Wr3;
  float v;
  if (k < 128)      v = Wg[k * DD + c] + Wr[k * DD + c];
  else if (k < 256) v = Wg[k * DD + c];
  else              v = Wl[(k - 256) * DD + c];
  Ut[(size_t)nn * KK + k] = f2bf(v);
  if (k == 0) {
    const float* bgp = g == 0 ? bg0 : g == 1 ? bg1 : g == 2 ? bg2 : bg3;
    const float* blp = g == 0 ? bl0 : g == 1 ? bl1 : g == 2 ? bl2 : bl3;
    bias[nn] = bgp[c] + blp[c];
  }
}

__device__ __forceinline__ void gload16(const void* g, void* l) {
  __builtin_amdgcn_global_load_lds((__attribute__((address_space(1))) void*)(void*)g,
                                   (__attribute__((address_space(3))) void*)l, 16, 0, 0);
}

// Fused GEMM + LSTM-gate + LayerNorm.
// BM=64, BN=512, BK=32; 512 threads = 8 waves, wave tile 64x64 (acc 64 VGPR).
// Double-buffered LDS (2 x 36KB), 2-phase pipeline: issue next-stage loads,
// compute current, single vmcnt(0)+barrier per K-step.
#define BUFB 36864
__global__ __launch_bounds__(512, 3) void k_gemm_fused(
    const unsigned short* __restrict__ hbf, const unsigned short* __restrict__ xbf,
    const unsigned short* __restrict__ aggbf, const unsigned short* __restrict__ Ut,
    const float* __restrict__ bias, const float* __restrict__ cell,
    const float* __restrict__ gamma, const float* __restrict__ beta,
    float* __restrict__ out, int nrows) {
  __shared__ char lds[2 * BUFB];  // 72KB; epilogue reuses first 64KB
  const int m0 = blockIdx.x * 64;
  const int tid = threadIdx.x;
  const int w = tid >> 6, lane = tid & 63;
  const int l15 = lane & 15, rg = lane >> 4;
  f32x4 acc[4][4] = {};

  const int sr = tid >> 2;   // staging row: A 0..63 (tid<256), B p*128+0..127
  const int slin = tid & 3;  // linear 16B slot within 64B row

  auto stage = [&](int ks, char* buf) {
    const unsigned short* Ab = ks < 4 ? hbf : (ks < 8 ? xbf : aggbf);
    const int akoff = (ks & 3) * 64;
    const int bkoff = ks * 64;
    if (tid < 256) {
      int d = slin ^ ((sr >> 1) & 3);  // pre-swizzled source slot
      gload16((const char*)Ab + (size_t)(m0 + sr) * 256 + akoff + d * 16, buf + tid * 16);
    }
#pragma unroll
    for (int p = 0; p < 4; ++p) {
      int r = p * 128 + sr;
      int d = slin ^ ((r >> 1) & 3);
      gload16((const char*)Ut + (size_t)r * 768 + bkoff + d * 16,
              buf + 4096 + p * 8192 + tid * 16);
    }
  };

  stage(0, lds);
  asm volatile("s_waitcnt vmcnt(0)" ::: "memory");
  __syncthreads();

#pragma unroll 1
  for (int ks = 0; ks < 12; ++ks) {
    char* cur = lds + (ks & 1) * BUFB;
    if (ks < 11) stage(ks + 1, lds + ((ks + 1) & 1) * BUFB);
    const char* As = cur;
    const char* Bs = cur + 4096;
    bf16x8 af[4], bq[4];
#pragma unroll
    for (int mi = 0; mi < 4; ++mi) {
      int r = mi * 16 + l15;
      af[mi] = *(const bf16x8*)(As + r * 64 + ((rg ^ ((r >> 1) & 3)) * 16));
    }
#pragma unroll
    for (int ni = 0; ni < 4; ++ni) {
      int r = w * 64 + ni * 16 + l15;
      bq[ni] = *(const bf16x8*)(Bs + r * 64 + ((rg ^ ((r >> 1) & 3)) * 16));
    }
#pragma unroll
    for (int mi = 0; mi < 4; ++mi)
#pragma unroll
      for (int ni = 0; ni < 4; ++ni)
        acc[mi][ni] = __builtin_amdgcn_mfma_f32_16x16x32_bf16(af[mi], bq[ni], acc[mi][ni], 0, 0, 0);
    asm volatile("s_waitcnt vmcnt(0)" ::: "memory");
    __syncthreads();
  }

  // stage gates (64 rows x 512 cols bf16, XOR-swizzled) into LDS
  float bias_v[4];
#pragma unroll
  for (int ni = 0; ni < 4; ++ni) bias_v[ni] = bias[w * 64 + ni * 16 + l15];
#pragma unroll
  for (int mi = 0; mi < 4; ++mi)
#pragma unroll
    for (int ni = 0; ni < 4; ++ni) {
      int col = w * 64 + ni * 16 + l15;
#pragma unroll
      for (int j = 0; j < 4; ++j) {
        int row = mi * 16 + rg * 4 + j;
        int byte = (row * 1024 + col * 2) ^ ((row & 7) << 4);
        *(unsigned short*)((char*)lds + byte) = f2bf(acc[mi][ni][j] + bias_v[ni]);
      }
    }
  __syncthreads();

#pragma unroll 1
  for (int t = 0; t < 8; ++t) {
    int rr = w * 8 + t;
    int rowg = m0 + rr;
    if (rowg >= nrows) continue;  // wave-uniform
    int c = lane * 2;
    int sw = (rr & 7) << 4;
    ushort2 fu = *(const ushort2*)((char*)lds + ((rr * 1024 + 0 + lane * 4) ^ sw));
    ushort2 iu = *(const ushort2*)((char*)lds + ((rr * 1024 + 256 + lane * 4) ^ sw));
    ushort2 cu = *(const ushort2*)((char*)lds + ((rr * 1024 + 512 + lane * 4) ^ sw));
    ushort2 ou = *(const ushort2*)((char*)lds + ((rr * 1024 + 768 + lane * 4) ^ sw));
    float2 cv = *(const float2*)(cell + (size_t)rowg * DD + c);
    float f0 = fsigmoid(bf2f(fu.x)), f1 = fsigmoid(bf2f(fu.y));
    float i0 = fsigmoid(bf2f(iu.x)), i1 = fsigmoid(bf2f(iu.y));
    float t0 = ftanh(bf2f(cu.x)), t1 = ftanh(bf2f(cu.y));
    float o0 = fsigmoid(bf2f(ou.x)), o1 = fsigmoid(bf2f(ou.y));
    float cn0 = f0 * cv.x + i0 * t0;
    float cn1 = f1 * cv.y + i1 * t1;
    float y0 = o0 * ftanh(cn0);
    float y1 = o1 * ftanh(cn1);
    float s = y0 + y1, s2 = y0 * y0 + y1 * y1;
#pragma unroll
    for (int off = 1; off < 64; off <<= 1) {
      s += __shfl_xor(s, off);
      s2 += __shfl_xor(s2, off);
    }
    float mean = s * (1.f / 128.f);
    float var = s2 * (1.f / 128.f) - mean * mean;
    float rstd = rsqrtf(var + 1e-5f);
    float2 gm = *(const float2*)(gamma + c);
    float2 bt = *(const float2*)(beta + c);
    float h0 = (y0 - mean) * rstd * gm.x + bt.x;
    float h1 = (y1 - mean) * rstd * gm.y + bt.y;
    *(float2*)(out + (size_t)rowg * DD + c) = make_float2(h0, h1);
    *(float2*)(out + (size_t)nrows * DD + (size_t)rowg * DD + c) = make_float2(cn0, cn1);
  }
}

extern "C" void kernel_launch(void* const* d_in, const int* in_sizes, int n_in,
                              void* d_out, int out_size, void* d_ws, size_t ws_size,
                              hipStream_t stream) {
  const float* h = (const float*)d_in[0];
  const float* cellp = (const float*)d_in[1];
  const float* x = (const float*)d_in[2];
  const int* edge = (const int*)d_in[3];
  const float* Wg0 = (const float*)d_in[4];
  const float* bg0 = (const float*)d_in[5];
  const float* Wg1 = (const float*)d_in[6];
  const float* bg1 = (const float*)d_in[7];
  const float* Wg2 = (const float*)d_in[8];
  const float* bg2 = (const float*)d_in[9];
  const float* Wg3 = (const float*)d_in[10];
  const float* bg3 = (const float*)d_in[11];
  const float* Wl0 = (const float*)d_in[12];
  const float* bl0 = (const float*)d_in[13];
  const float* Wr0 = (const float*)d_in[14];
  const float* Wl1 = (const float*)d_in[15];
  const float* bl1 = (const float*)d_in[16];
  const float* Wr1 = (const float*)d_in[17];
  const float* Wl2 = (const float*)d_in[18];
  const float* bl2 = (const float*)d_in[19];
  const float* Wr2 = (const float*)d_in[20];
  const float* Wl3 = (const float*)d_in[21];
  const float* bl3 = (const float*)d_in[22];
  const float* Wr3 = (const float*)d_in[23];
  const float* gamma = (const float*)d_in[24];
  const float* beta = (const float*)d_in[25];

  int N = in_sizes[0] / DD;
  int E = in_sizes[3] / 2;
  int Mpad = ((N + 127) / 128) * 128;

  char* ws = (char*)d_ws;
  size_t off = 0;
  auto alloc = [&](size_t b) {
    char* p = ws + off;
    off += (b + 255) & ~(size_t)255;
    return p;
  };
  int* counts = (int*)alloc((size_t)N * 4);
  int* cursor = (int*)alloc((size_t)N * 4);
  int* row_start = (int*)alloc((size_t)N * 4);
  int* gcur = (int*)alloc(4);
  int* csr = (int*)alloc((size_t)E * 4);
  unsigned short* hbf = (unsigned short*)alloc((size_t)Mpad * DD * 2);
  unsigned short* xbf = (unsigned short*)alloc((size_t)Mpad * DD * 2);
  unsigned short* aggbf = (unsigned short*)alloc((size_t)Mpad * DD * 2);
  unsigned short* Ut = (unsigned short*)alloc((size_t)NG * KK * 2);
  float* bias = (float*)alloc((size_t)NG * 4);
  (void)ws_size;
  (void)n_in;
  (void)out_size;

  const int* esrc = edge;
  const int* edst = edge + E;

  k_zero2<<<(N + 255) / 256, 256, 0, stream>>>(counts, cursor, gcur, N);
  k_count<<<(E + 255) / 256, 256, 0, stream>>>(edst, counts, E);
  k_partition<<<(N + 255) / 256, 256, 0, stream>>>(counts, row_start, gcur, N);
  k_scatter<<<(E + 255) / 256, 256, 0, stream>>>(esrc, edst, row_start, cursor, csr, E);
  k_convert<<<((Mpad * DD / 4) + 255) / 256, 256, 0, stream>>>(h, x, hbf, xbf, N * DD, Mpad * DD);
  k_agg<<<(Mpad + 3) / 4, 256, 0, stream>>>(hbf, row_start, counts, csr, aggbf, N, Mpad);
  k_fusew<<<(NG * KK + 255) / 256, 256, 0, stream>>>(
      Wg0, Wg1, Wg2, Wg3, Wl0, Wl1, Wl2, Wl3, Wr0, Wr1, Wr2, Wr3,
      bg0, bg1, bg2, bg3, bl0, bl1, bl2, bl3, Ut, bias);
  k_gemm_fused<<<Mpad / 64, 512, 0, stream>>>(hbf, xbf, aggbf, Ut, bias, cellp,
                                              gamma, beta, (float*)d_out, N);
}

// Round 5
// 211.267 us; speedup vs baseline: 1.2957x; 1.0029x over previous
//
#include <hip/hip_runtime.h>

#define DD 128
#define KK 384
#define NG 512

typedef __attribute__((ext_vector_type(8))) short bf16x8;
typedef __attribute__((ext_vector_type(4))) float f32x4;

__device__ __forceinline__ float bf2f(unsigned short u) {
  return __uint_as_float(((unsigned int)u) << 16);
}
__device__ __forceinline__ unsigned short f2bf(float f) {
  unsigned int x = __float_as_uint(f);
  x += 0x7fffu + ((x >> 16) & 1u);
  return (unsigned short)(x >> 16);
}
__device__ __forceinline__ float fsigmoid(float v) {
  return 1.f / (1.f + __expf(-v));
}
__device__ __forceinline__ float ftanh(float v) {
  float t = __expf(2.f * v);
  return (t - 1.f) / (t + 1.f);
}

__global__ void k_zero2(int* __restrict__ a, int* __restrict__ b,
                        int* __restrict__ gcur, int n) {
  int i = blockIdx.x * blockDim.x + threadIdx.x;
  if (i < n) { a[i] = 0; b[i] = 0; }
  if (i == 0) *gcur = 0;
}

__global__ void k_count(const int* __restrict__ dst, int* __restrict__ counts, int E) {
  int e = blockIdx.x * blockDim.x + threadIdx.x;
  if (e < E) atomicAdd(counts + dst[e], 1);
}

__global__ void k_partition(const int* __restrict__ counts, int* __restrict__ row_start,
                            int* __restrict__ gcur, int n) {
  int i = blockIdx.x * blockDim.x + threadIdx.x;
  int lane = threadIdx.x & 63;
  int v = (i < n) ? counts[i] : 0;
  int s = v;
#pragma unroll
  for (int off = 1; off < 64; off <<= 1) {
    int t = __shfl_up(s, off);
    if (lane >= off) s += t;
  }
  int total = __shfl(s, 63);
  int base = 0;
  if (lane == 63) base = atomicAdd(gcur, total);
  base = __shfl(base, 63);
  if (i < n) row_start[i] = base + s - v;
}

__global__ void k_scatter(const int* __restrict__ srcv, const int* __restrict__ dstv,
                          const int* __restrict__ row_start, int* __restrict__ cursor,
                          int* __restrict__ csr, int E) {
  int e = blockIdx.x * blockDim.x + threadIdx.x;
  if (e < E) {
    int d = dstv[e];
    int pos = row_start[d] + atomicAdd(cursor + d, 1);
    csr[pos] = srcv[e];
  }
}

__global__ void k_convert(const float* __restrict__ h, const float* __restrict__ x,
                          unsigned short* __restrict__ hbf, unsigned short* __restrict__ xbf,
                          int n128, int mpad128) {
  int i = (blockIdx.x * blockDim.x + threadIdx.x) * 4;
  if (i >= mpad128) return;
  ushort4 ho, xo;
  if (i < n128) {
    float4 hv = *(const float4*)(h + i);
    float4 xv = *(const float4*)(x + i);
    ho = make_ushort4(f2bf(hv.x), f2bf(hv.y), f2bf(hv.z), f2bf(hv.w));
    xo = make_ushort4(f2bf(xv.x), f2bf(xv.y), f2bf(xv.z), f2bf(xv.w));
  } else {
    ho = make_ushort4(0, 0, 0, 0);
    xo = make_ushort4(0, 0, 0, 0);
  }
  *(ushort4*)(hbf + i) = ho;
  *(ushort4*)(xbf + i) = xo;
}

// One wave per node. 4 neighbor-groups x 16 lanes x bf16x8(16B) per row.
__global__ void k_agg(const unsigned short* __restrict__ hbf, const int* __restrict__ row_start,
                      const int* __restrict__ counts, const int* __restrict__ csr,
                      unsigned short* __restrict__ aggbf, int n, int mpad) {
  int wave = (blockIdx.x * blockDim.x + threadIdx.x) >> 6;
  int lane = threadIdx.x & 63;
  if (wave >= mpad) return;
  int g = lane >> 4;
  int t = lane & 15;
  float acc[8] = {0.f, 0.f, 0.f, 0.f, 0.f, 0.f, 0.f, 0.f};
  if (wave < n) {
    int s = row_start[wave], deg = counts[wave];
    int e = s + deg;
    for (int j = s; j < e; j += 4) {
      int jj = j + g;
      if (jj < e) {
        int src = csr[jj];
        bf16x8 v = *(const bf16x8*)(hbf + (size_t)src * DD + t * 8);
#pragma unroll
        for (int q = 0; q < 8; ++q) acc[q] += bf2f((unsigned short)v[q]);
      }
    }
#pragma unroll
    for (int q = 0; q < 8; ++q) {
      acc[q] += __shfl_xor(acc[q], 16);
      acc[q] += __shfl_xor(acc[q], 32);
    }
    float inv = 1.f / fmaxf((float)deg, 1.f);
#pragma unroll
    for (int q = 0; q < 8; ++q) acc[q] *= inv;
  }
  if (g == 0) {
    bf16x8 o;
#pragma unroll
    for (int q = 0; q < 8; ++q) o[q] = (short)f2bf(acc[q]);
    *(bf16x8*)(aggbf + (size_t)wave * DD + t * 8) = o;
  }
}

__global__ void k_fusew(const float* __restrict__ Wg0, const float* __restrict__ Wg1,
                        const float* __restrict__ Wg2, const float* __restrict__ Wg3,
                        const float* __restrict__ Wl0, const float* __restrict__ Wl1,
                        const float* __restrict__ Wl2, const float* __restrict__ Wl3,
                        const float* __restrict__ Wr0, const float* __restrict__ Wr1,
                        const float* __restrict__ Wr2, const float* __restrict__ Wr3,
                        const float* __restrict__ bg0, const float* __restrict__ bg1,
                        const float* __restrict__ bg2, const float* __restrict__ bg3,
                        const float* __restrict__ bl0, const float* __restrict__ bl1,
                        const float* __restrict__ bl2, const float* __restrict__ bl3,
                        unsigned short* __restrict__ Ut, float* __restrict__ bias) {
  int id = blockIdx.x * blockDim.x + threadIdx.x;
  if (id >= NG * KK) return;
  int nn = id / KK, k = id % KK;
  int g = nn >> 7, c = nn & 127;
  const float* Wg = g == 0 ? Wg0 : g == 1 ? Wg1 : g == 2 ? Wg2 : Wg3;
  const float* Wl = g == 0 ? Wl0 : g == 1 ? Wl1 : g == 2 ? Wl2 : Wl3;
  const float* Wr = g == 0 ? Wr0 : g == 1 ? Wr1 : g == 2 ? Wr2 : Wr3;
  float v;
  if (k < 128)      v = Wg[k * DD + c] + Wr[k * DD + c];
  else if (k < 256) v = Wg[k * DD + c];
  else              v = Wl[(k - 256) * DD + c];
  Ut[(size_t)nn * KK + k] = f2bf(v);
  if (k == 0) {
    const float* bgp = g == 0 ? bg0 : g == 1 ? bg1 : g == 2 ? bg2 : bg3;
    const float* blp = g == 0 ? bl0 : g == 1 ? bl1 : g == 2 ? bl2 : bl3;
    bias[nn] = bgp[c] + blp[c];
  }
}

__device__ __forceinline__ void gload16(const void* g, void* l) {
  __builtin_amdgcn_global_load_lds((__attribute__((address_space(1))) void*)(void*)g,
                                   (__attribute__((address_space(3))) void*)l, 16, 0, 0);
}

// Fused GEMM + LSTM-gate + LayerNorm.
// BM=128, BN=512, BK=64; 1024 threads = 16 waves (2Mx8N), wave tile 64x64.
// LDS: A 16KB single + B 2x64KB double-buffered = 144KB (1 block/CU).
// Counted-vmcnt pipeline: loads stay in flight across raw s_barriers.
#define ABUF 0
#define BBUF0 16384
#define BBUF1 81920
__global__ __launch_bounds__(1024, 4) void k_gemm_fused(
    const unsigned short* __restrict__ hbf, const unsigned short* __restrict__ xbf,
    const unsigned short* __restrict__ aggbf, const unsigned short* __restrict__ Ut,
    const float* __restrict__ bias, const float* __restrict__ cell,
    const float* __restrict__ gamma, const float* __restrict__ beta,
    float* __restrict__ out, int nrows) {
  __shared__ char lds[147456];  // 144KB; epilogue reuses first 128KB
  const int m0 = blockIdx.x * 128;
  const int tid = threadIdx.x;
  const int w = tid >> 6, lane = tid & 63;
  const int wr = w >> 3, wc = w & 7;
  const int l15 = lane & 15, rg = lane >> 4;
  f32x4 acc[4][4] = {};

  const int srow = tid >> 3;   // 0..127 staging row
  const int sslot = tid & 7;   // 16B slot in 128B row

  // stage A(ks) into ABUF: 1 load/thread
  auto stageA = [&](int ks) {
    const unsigned short* Ab = ks < 2 ? hbf : (ks < 4 ? xbf : aggbf);
    const int akoff = (ks & 1) * 128;
    int d = sslot ^ (srow & 7);
    gload16((const char*)Ab + (size_t)(m0 + srow) * 256 + akoff + d * 16,
            lds + ABUF + tid * 16);
  };
  // stage B(ks) into buf: 4 loads/thread
  auto stageB = [&](int ks, int bbase) {
    const int bkoff = ks * 128;
#pragma unroll
    for (int p = 0; p < 4; ++p) {
      int r = p * 128 + srow;
      int d = sslot ^ (r & 7);
      gload16((const char*)Ut + (size_t)r * 768 + bkoff + d * 16,
              lds + bbase + p * 16384 + tid * 16);
    }
  };

  // prologue: B(0), A(0), B(1) in flight; wait for B(0)+A(0)
  stageB(0, BBUF0);
  stageA(0);
  stageB(1, BBUF1);
  asm volatile("s_waitcnt vmcnt(4)" ::: "memory");
  __builtin_amdgcn_sched_barrier(0);
  __builtin_amdgcn_s_barrier();

#pragma unroll
  for (int ks = 0; ks < 6; ++ks) {
    const char* As = lds + ABUF;
    const char* Bs = lds + (ks & 1 ? BBUF1 : BBUF0);
    // ---- slice 0 ----
    bf16x8 af0[4], bq0[4];
#pragma unroll
    for (int mi = 0; mi < 4; ++mi) {
      int r = wr * 64 + mi * 16 + l15;
      af0[mi] = *(const bf16x8*)(As + r * 128 + ((rg ^ (r & 7)) * 16));
    }
#pragma unroll
    for (int ni = 0; ni < 4; ++ni) {
      int r = wc * 64 + ni * 16 + l15;
      bq0[ni] = *(const bf16x8*)(Bs + r * 128 + ((rg ^ (r & 7)) * 16));
    }
#pragma unroll
    for (int mi = 0; mi < 4; ++mi)
#pragma unroll
      for (int ni = 0; ni < 4; ++ni)
        acc[mi][ni] = __builtin_amdgcn_mfma_f32_16x16x32_bf16(af0[mi], bq0[ni], acc[mi][ni], 0, 0, 0);
    // ---- slice 1 ----
    bf16x8 af1[4], bq1[4];
#pragma unroll
    for (int mi = 0; mi < 4; ++mi) {
      int r = wr * 64 + mi * 16 + l15;
      af1[mi] = *(const bf16x8*)(As + r * 128 + (((4 + rg) ^ (r & 7)) * 16));
    }
#pragma unroll
    for (int ni = 0; ni < 4; ++ni) {
      int r = wc * 64 + ni * 16 + l15;
      bq1[ni] = *(const bf16x8*)(Bs + r * 128 + (((4 + rg) ^ (r & 7)) * 16));
    }
    // all LDS reads of this step done before anyone restages these buffers
    asm volatile("s_waitcnt lgkmcnt(0)" ::: "memory");
    __builtin_amdgcn_sched_barrier(0);
    __builtin_amdgcn_s_barrier();
    if (ks < 5) stageA(ks + 1);
    if (ks < 4) stageB(ks + 2, (ks & 1) ? BBUF1 : BBUF0);
#pragma unroll
    for (int mi = 0; mi < 4; ++mi)
#pragma unroll
      for (int ni = 0; ni < 4; ++ni)
        acc[mi][ni] = __builtin_amdgcn_mfma_f32_16x16x32_bf16(af1[mi], bq1[ni], acc[mi][ni], 0, 0, 0);
    if (ks < 4) {
      asm volatile("s_waitcnt vmcnt(4)" ::: "memory");  // A(k+1)+B(k+1) landed
    } else if (ks == 4) {
      asm volatile("s_waitcnt vmcnt(0)" ::: "memory");
    }
    __builtin_amdgcn_sched_barrier(0);
    __builtin_amdgcn_s_barrier();
  }

  // stage gates (128 rows x 512 cols bf16, XOR-swizzled) into LDS[0..128KB)
  float bias_v[4];
#pragma unroll
  for (int ni = 0; ni < 4; ++ni) bias_v[ni] = bias[wc * 64 + ni * 16 + l15];
#pragma unroll
  for (int mi = 0; mi < 4; ++mi)
#pragma unroll
    for (int ni = 0; ni < 4; ++ni) {
      int col = wc * 64 + ni * 16 + l15;
#pragma unroll
      for (int j = 0; j < 4; ++j) {
        int row = wr * 64 + mi * 16 + rg * 4 + j;
        int byte = (row * 1024 + col * 2) ^ ((row & 7) << 4);
        *(unsigned short*)(lds + byte) = f2bf(acc[mi][ni][j] + bias_v[ni]);
      }
    }
  asm volatile("s_waitcnt lgkmcnt(0)" ::: "memory");
  __builtin_amdgcn_sched_barrier(0);
  __builtin_amdgcn_s_barrier();

#pragma unroll 1
  for (int t = 0; t < 8; ++t) {
    int rr = w * 8 + t;
    int rowg = m0 + rr;
    if (rowg >= nrows) continue;  // wave-uniform
    int c = lane * 2;
    int sw = (rr & 7) << 4;
    ushort2 fu = *(const ushort2*)(lds + ((rr * 1024 + 0 + lane * 4) ^ sw));
    ushort2 iu = *(const ushort2*)(lds + ((rr * 1024 + 256 + lane * 4) ^ sw));
    ushort2 cu = *(const ushort2*)(lds + ((rr * 1024 + 512 + lane * 4) ^ sw));
    ushort2 ou = *(const ushort2*)(lds + ((rr * 1024 + 768 + lane * 4) ^ sw));
    float2 cv = *(const float2*)(cell + (size_t)rowg * DD + c);
    float f0 = fsigmoid(bf2f(fu.x)), f1 = fsigmoid(bf2f(fu.y));
    float i0 = fsigmoid(bf2f(iu.x)), i1 = fsigmoid(bf2f(iu.y));
    float t0 = ftanh(bf2f(cu.x)), t1 = ftanh(bf2f(cu.y));
    float o0 = fsigmoid(bf2f(ou.x)), o1 = fsigmoid(bf2f(ou.y));
    float cn0 = f0 * cv.x + i0 * t0;
    float cn1 = f1 * cv.y + i1 * t1;
    float y0 = o0 * ftanh(cn0);
    float y1 = o1 * ftanh(cn1);
    float s = y0 + y1, s2 = y0 * y0 + y1 * y1;
#pragma unroll
    for (int off = 1; off < 64; off <<= 1) {
      s += __shfl_xor(s, off);
      s2 += __shfl_xor(s2, off);
    }
    float mean = s * (1.f / 128.f);
    float var = s2 * (1.f / 128.f) - mean * mean;
    float rstd = rsqrtf(var + 1e-5f);
    float2 gm = *(const float2*)(gamma + c);
    float2 bt = *(const float2*)(beta + c);
    float h0 = (y0 - mean) * rstd * gm.x + bt.x;
    float h1 = (y1 - mean) * rstd * gm.y + bt.y;
    *(float2*)(out + (size_t)rowg * DD + c) = make_float2(h0, h1);
    *(float2*)(out + (size_t)nrows * DD + (size_t)rowg * DD + c) = make_float2(cn0, cn1);
  }
}

extern "C" void kernel_launch(void* const* d_in, const int* in_sizes, int n_in,
                              void* d_out, int out_size, void* d_ws, size_t ws_size,
                              hipStream_t stream) {
  const float* h = (const float*)d_in[0];
  const float* cellp = (const float*)d_in[1];
  const float* x = (const float*)d_in[2];
  const int* edge = (const int*)d_in[3];
  const float* Wg0 = (const float*)d_in[4];
  const float* bg0 = (const float*)d_in[5];
  const float* Wg1 = (const float*)d_in[6];
  const float* bg1 = (const float*)d_in[7];
  const float* Wg2 = (const float*)d_in[8];
  const float* bg2 = (const float*)d_in[9];
  const float* Wg3 = (const float*)d_in[10];
  const float* bg3 = (const float*)d_in[11];
  const float* Wl0 = (const float*)d_in[12];
  const float* bl0 = (const float*)d_in[13];
  const float* Wr0 = (const float*)d_in[14];
  const float* Wl1 = (const float*)d_in[15];
  const float* bl1 = (const float*)d_in[16];
  const float* Wr1 = (const float*)d_in[17];
  const float* Wl2 = (const float*)d_in[18];
  const float* bl2 = (const float*)d_in[19];
  const float* Wr2 = (const float*)d_in[20];
  const float* Wl3 = (const float*)d_in[21];
  const float* bl3 = (const float*)d_in[22];
  const float* Wr3 = (const float*)d_in[23];
  const float* gamma = (const float*)d_in[24];
  const float* beta = (const float*)d_in[25];

  int N = in_sizes[0] / DD;
  int E = in_sizes[3] / 2;
  int Mpad = ((N + 127) / 128) * 128;

  char* ws = (char*)d_ws;
  size_t off = 0;
  auto alloc = [&](size_t b) {
    char* p = ws + off;
    off += (b + 255) & ~(size_t)255;
    return p;
  };
  int* counts = (int*)alloc((size_t)N * 4);
  int* cursor = (int*)alloc((size_t)N * 4);
  int* row_start = (int*)alloc((size_t)N * 4);
  int* gcur = (int*)alloc(4);
  int* csr = (int*)alloc((size_t)E * 4);
  unsigned short* hbf = (unsigned short*)alloc((size_t)Mpad * DD * 2);
  unsigned short* xbf = (unsigned short*)alloc((size_t)Mpad * DD * 2);
  unsigned short* aggbf = (unsigned short*)alloc((size_t)Mpad * DD * 2);
  unsigned short* Ut = (unsigned short*)alloc((size_t)NG * KK * 2);
  float* bias = (float*)alloc((size_t)NG * 4);
  (void)ws_size;
  (void)n_in;
  (void)out_size;

  const int* esrc = edge;
  const int* edst = edge + E;

  k_zero2<<<(N + 255) / 256, 256, 0, stream>>>(counts, cursor, gcur, N);
  k_count<<<(E + 255) / 256, 256, 0, stream>>>(edst, counts, E);
  k_partition<<<(N + 255) / 256, 256, 0, stream>>>(counts, row_start, gcur, N);
  k_scatter<<<(E + 255) / 256, 256, 0, stream>>>(esrc, edst, row_start, cursor, csr, E);
  k_convert<<<((Mpad * DD / 4) + 255) / 256, 256, 0, stream>>>(h, x, hbf, xbf, N * DD, Mpad * DD);
  k_agg<<<(Mpad + 3) / 4, 256, 0, stream>>>(hbf, row_start, counts, csr, aggbf, N, Mpad);
  k_fusew<<<(NG * KK + 255) / 256, 256, 0, stream>>>(
      Wg0, Wg1, Wg2, Wg3, Wl0, Wl1, Wl2, Wl3, Wr0, Wr1, Wr2, Wr3,
      bg0, bg1, bg2, bg3, bl0, bl1, bl2, bl3, Ut, bias);
  k_gemm_fused<<<Mpad / 128, 1024, 0, stream>>>(hbf, xbf, aggbf, Ut, bias, cellp,
                                                gamma, beta, (float*)d_out, N);
}